// Round 2
// baseline (930.152 us; speedup 1.0000x reference)
//
#include <hip/hip_runtime.h>
#include <hip/hip_bf16.h>
#include <stdint.h>

#define T_TOK 4096
#define HDIM  2048
#define IDIM  1408
#define NEXP  8
#define SIDIM 2816
#define BKG   32

typedef __bf16 bf16_t;
typedef __bf16 bf16x8 __attribute__((ext_vector_type(8)));
typedef __bf16 bf16x4 __attribute__((ext_vector_type(4)));
typedef float  f32x4  __attribute__((ext_vector_type(4)));

typedef uint32_t __attribute__((address_space(3))) lds_u32;
typedef uint32_t __attribute__((address_space(1))) glb_u32;

__device__ __forceinline__ void glds16(const bf16_t* g, const bf16_t* l) {
  __builtin_amdgcn_global_load_lds((const glb_u32*)g, (lds_u32*)l, 16, 0, 0);
}

// m204 bijective XCD swizzle: hw assigns XCD by (linear % 8); this maps the
// origs resident on one XCD to a CONTIGUOUS logical range, so consecutive
// logical tiles (which share a weight panel) run on the same XCD's L2.
__device__ __forceinline__ int xcd_swz(int orig, int nwg) {
  int q = nwg >> 3, r = nwg & 7;
  int x = orig & 7, i = orig >> 3;
  return (x < r ? x * (q + 1) : r * (q + 1) + (x - r) * q) + i;
}

// ---------------- convert x (f32 -> bf16) ----------------
__global__ void cvt_x_kernel(const float4* __restrict__ in, bf16x4* __restrict__ out, int n4) {
  int i = blockIdx.x * 256 + threadIdx.x;
  if (i >= n4) return;
  float4 v = in[i];
  bf16x4 o;
  o[0] = (bf16_t)v.x; o[1] = (bf16_t)v.y; o[2] = (bf16_t)v.z; o[3] = (bf16_t)v.w;
  out[i] = o;
}

// ---------------- transpose+convert: f32 [R][C] -> bf16 [C][R], batched in z ----------------
__global__ void tcvt_kernel(const float* __restrict__ in, bf16_t* __restrict__ out, int R, int C) {
  in  += (size_t)blockIdx.z * R * C;
  out += (size_t)blockIdx.z * R * C;
  __shared__ bf16_t t[64][72];
  const int r0 = blockIdx.y * 64, c0 = blockIdx.x * 64;
  const int tid = threadIdx.x;
  const int cf4 = tid & 15;
  const int rr  = tid >> 4;
#pragma unroll
  for (int s = 0; s < 4; ++s) {
    int r = rr + 16 * s;
    float4 v = *(const float4*)(in + (size_t)(r0 + r) * C + c0 + cf4 * 4);
    t[cf4 * 4 + 0][r] = (bf16_t)v.x;
    t[cf4 * 4 + 1][r] = (bf16_t)v.y;
    t[cf4 * 4 + 2][r] = (bf16_t)v.z;
    t[cf4 * 4 + 3][r] = (bf16_t)v.w;
  }
  __syncthreads();
  const int c  = tid >> 2;
  const int rb = (tid & 3) * 16;
  bf16x8 w0 = *(const bf16x8*)&t[c][rb];
  bf16x8 w1 = *(const bf16x8*)&t[c][rb + 8];
  bf16_t* op = out + (size_t)(c0 + c) * R + r0 + rb;
  *(bf16x8*)op = w0;
  *(bf16x8*)(op + 8) = w1;
}

// ---------------- router ----------------
__global__ void router_kernel(const float* __restrict__ x, const float* __restrict__ rw,
                              int* __restrict__ tk_i, float* __restrict__ tk_w,
                              int* __restrict__ counts) {
  int gtid = blockIdx.x * 256 + threadIdx.x;
  int t = gtid >> 6, lane = gtid & 63;
  const float4* xr = (const float4*)(x + (size_t)t * HDIM);
  float acc[NEXP];
#pragma unroll
  for (int e = 0; e < NEXP; e++) acc[e] = 0.f;
  for (int i = lane; i < HDIM / 4; i += 64) {
    float4 xv = xr[i];
#pragma unroll
    for (int e = 0; e < NEXP; e++) {
      float4 wv = ((const float4*)(rw + e * HDIM))[i];
      acc[e] += xv.x * wv.x + xv.y * wv.y + xv.z * wv.z + xv.w * wv.w;
    }
  }
#pragma unroll
  for (int e = 0; e < NEXP; e++)
#pragma unroll
    for (int off = 32; off; off >>= 1) acc[e] += __shfl_down(acc[e], off);
  if (lane == 0) {
    int i1 = 0; float m1 = acc[0];
#pragma unroll
    for (int e = 1; e < NEXP; e++) if (acc[e] > m1) { m1 = acc[e]; i1 = e; }
    int i2 = -1; float m2 = -1e30f;
#pragma unroll
    for (int e = 0; e < NEXP; e++) if (e != i1 && acc[e] > m2) { m2 = acc[e]; i2 = e; }
    float w1 = 1.f / (1.f + __expf(m2 - m1));
    tk_i[t * 2] = i1; tk_i[t * 2 + 1] = i2;
    tk_w[t * 2] = w1; tk_w[t * 2 + 1] = 1.f - w1;
    atomicAdd(&counts[i1], 1); atomicAdd(&counts[i2], 1);
  }
}

__global__ void offs_kernel(const int* __restrict__ counts, int* __restrict__ offs) {
  if (threadIdx.x == 0 && blockIdx.x == 0) {
    int o = 0;
    for (int e = 0; e < NEXP; e++) { offs[e] = o; o += counts[e]; }
    offs[NEXP] = o;
  }
}

__global__ void scatter_kernel(const int* __restrict__ tk_i, const float* __restrict__ tk_w,
                               const int* __restrict__ offs, int* __restrict__ cursor,
                               int* __restrict__ tok_idx, float* __restrict__ tok_w) {
  int t = blockIdx.x * 256 + threadIdx.x;
  if (t >= T_TOK) return;
#pragma unroll
  for (int k = 0; k < 2; k++) {
    int e = tk_i[t * 2 + k];
    int pos = offs[e] + atomicAdd(&cursor[e], 1);
    tok_idx[pos] = t; tok_w[pos] = tk_w[t * 2 + k];
  }
}

// ---------------- fused gate/up GEMM + SwiGLU, prefetch-pipelined ----------------
template <bool GATHER>
__global__ __launch_bounds__(256)
void gateup_kernel(const bf16_t* __restrict__ X, const bf16_t* __restrict__ GT,
                   const bf16_t* __restrict__ UT, const float* __restrict__ bg,
                   const float* __restrict__ bu, const int* __restrict__ offs,
                   const int* __restrict__ tok_idx, bf16_t* __restrict__ Hout,
                   int N, int K) {
  const int e = blockIdx.z;
  int cnt, slot0;
  if (GATHER) {
    slot0 = offs[e];
    cnt = offs[e + 1] - slot0;
  } else { cnt = T_TOK; slot0 = 0; }

  const int nx  = gridDim.x;                  // col blocks
  const int arb = (cnt + 127) >> 7;           // active row blocks
  const int nwg = arb * nx;
  const int l   = blockIdx.x + nx * blockIdx.y;
  if (l >= nwg) return;
  const int s = xcd_swz(l, nwg);
  const int row0 = (s % arb) * 128;           // row fastest: consecutive s share panel
  const int n0   = (s / arb) * 128;

  const bf16_t* Gp = GT + (size_t)e * N * K;
  const bf16_t* Up = UT + (size_t)e * N * K;

  __shared__ bf16_t sA[2][128 * BKG];
  __shared__ bf16_t sG[2][128 * BKG];
  __shared__ bf16_t sU[2][128 * BKG];

  const int tid = threadIdx.x;
  const int wave = tid >> 6, lane = tid & 63;
  const int c0  = wave * 2;                   // two 16-row chunks per wave
  const int lr4 = lane >> 2;                  // row within chunk
  const int lk8 = (lane & 3) * 8;             // k offset

  const bf16_t *pA0, *pA1, *pG0, *pG1, *pU0, *pU1;
  {
    int r0c = c0 * 16 + lr4, r1c = r0c + 16;
    int arow0, arow1;
    if (GATHER) {
      int rr0 = row0 + r0c; if (rr0 >= cnt) rr0 = cnt - 1;
      int rr1 = row0 + r1c; if (rr1 >= cnt) rr1 = cnt - 1;
      arow0 = tok_idx[slot0 + rr0]; arow1 = tok_idx[slot0 + rr1];
    } else { arow0 = row0 + r0c; arow1 = row0 + r1c; }
    pA0 = X + (size_t)arow0 * K + lk8;
    pA1 = X + (size_t)arow1 * K + lk8;
    pG0 = Gp + (size_t)(n0 + r0c) * K + lk8;
    pG1 = Gp + (size_t)(n0 + r1c) * K + lk8;
    pU0 = Up + (size_t)(n0 + r0c) * K + lk8;
    pU1 = Up + (size_t)(n0 + r1c) * K + lk8;
  }
  bf16_t* sAb = &sA[0][0];
  bf16_t* sGb = &sG[0][0];
  bf16_t* sUb = &sU[0][0];

  auto STAGE = [&](int buf, int kt) {
    const int kk = kt * BKG;
    const int boff = buf * (128 * BKG);
    glds16(pA0 + kk, sAb + boff + (c0    ) * 512);
    glds16(pA1 + kk, sAb + boff + (c0 + 1) * 512);
    glds16(pG0 + kk, sGb + boff + (c0    ) * 512);
    glds16(pG1 + kk, sGb + boff + (c0 + 1) * 512);
    glds16(pU0 + kk, sUb + boff + (c0    ) * 512);
    glds16(pU1 + kk, sUb + boff + (c0 + 1) * 512);
  };

  f32x4 accg[4][4], accu[4][4];
#pragma unroll
  for (int mi = 0; mi < 4; mi++)
#pragma unroll
    for (int ni = 0; ni < 4; ni++) { accg[mi][ni] = (f32x4)(0.f); accu[mi][ni] = (f32x4)(0.f); }

  const int wr = wave >> 1, wc = wave & 1;
  const int lr = lane & 15, lg = lane >> 4;
  const int NKI = K / BKG;

  STAGE(0, 0);
  __syncthreads();
  int cur = 0;
  for (int kt = 0; kt < NKI; ++kt) {
    if (kt + 1 < NKI) STAGE(cur ^ 1, kt + 1);
    const bf16_t* sa = sAb + cur * (128 * BKG);
    const bf16_t* sg = sGb + cur * (128 * BKG);
    const bf16_t* su = sUb + cur * (128 * BKG);
    bf16x8 af[4];
#pragma unroll
    for (int mi = 0; mi < 4; mi++)
      af[mi] = *(const bf16x8*)&sa[(wr * 64 + mi * 16 + lr) * BKG + lg * 8];
#pragma unroll
    for (int ni = 0; ni < 4; ni++) {
      bf16x8 gf = *(const bf16x8*)&sg[(wc * 64 + ni * 16 + lr) * BKG + lg * 8];
      bf16x8 uf = *(const bf16x8*)&su[(wc * 64 + ni * 16 + lr) * BKG + lg * 8];
#pragma unroll
      for (int mi = 0; mi < 4; mi++)
        accg[mi][ni] = __builtin_amdgcn_mfma_f32_16x16x32_bf16(af[mi], gf, accg[mi][ni], 0, 0, 0);
#pragma unroll
      for (int mi = 0; mi < 4; mi++)
        accu[mi][ni] = __builtin_amdgcn_mfma_f32_16x16x32_bf16(af[mi], uf, accu[mi][ni], 0, 0, 0);
    }
    __syncthreads();
    cur ^= 1;
  }

#pragma unroll
  for (int mi = 0; mi < 4; mi++) {
#pragma unroll
    for (int j = 0; j < 4; j++) {
      int rl = wr * 64 + mi * 16 + lg * 4 + j;
      int grow = row0 + rl;
      if (GATHER && grow >= cnt) continue;
      size_t orow = (size_t)(slot0 + grow) * N;
#pragma unroll
      for (int ni = 0; ni < 4; ni++) {
        int col = n0 + wc * 64 + ni * 16 + lr;
        float g = accg[mi][ni][j];
        float u = accu[mi][ni][j];
        if (!GATHER) { g += bg[col]; u += bu[col]; }
        float h = (g / (1.f + __expf(-g))) * u;
        Hout[orow + col] = (bf16_t)h;
      }
    }
  }
}

// ---------------- down-projection GEMM, prefetch-pipelined ----------------
template <bool GATHER>
__global__ __launch_bounds__(256)
void down_kernel(const bf16_t* __restrict__ Hin, const bf16_t* __restrict__ DT,
                 const float* __restrict__ bias, const int* __restrict__ offs,
                 const int* __restrict__ tok_idx, const float* __restrict__ tok_w,
                 float* __restrict__ out, int K) {
  const int N = HDIM;
  const int e = blockIdx.z;
  int cnt, slot0;
  if (GATHER) {
    slot0 = offs[e];
    cnt = offs[e + 1] - slot0;
  } else { cnt = T_TOK; slot0 = 0; }

  const int nx  = gridDim.x;
  const int arb = (cnt + 127) >> 7;
  const int nwg = arb * nx;
  const int l   = blockIdx.x + nx * blockIdx.y;
  if (l >= nwg) return;
  const int s = xcd_swz(l, nwg);
  const int row0 = (s % arb) * 128;
  const int n0   = (s / arb) * 128;

  const bf16_t* Dp = DT + (size_t)e * N * K;

  __shared__ bf16_t sA[2][128 * BKG];
  __shared__ bf16_t sB[2][128 * BKG];

  const int tid = threadIdx.x;
  const int wave = tid >> 6, lane = tid & 63;
  const int c0  = wave * 2;
  const int lr4 = lane >> 2;
  const int lk8 = (lane & 3) * 8;

  const bf16_t *pA0, *pA1, *pB0, *pB1;
  {
    int r0c = c0 * 16 + lr4, r1c = r0c + 16;
    int rr0 = row0 + r0c, rr1 = row0 + r1c;
    if (GATHER) { if (rr0 >= cnt) rr0 = cnt - 1; if (rr1 >= cnt) rr1 = cnt - 1; }
    pA0 = Hin + (size_t)(slot0 + rr0) * K + lk8;
    pA1 = Hin + (size_t)(slot0 + rr1) * K + lk8;
    pB0 = Dp + (size_t)(n0 + r0c) * K + lk8;
    pB1 = Dp + (size_t)(n0 + r1c) * K + lk8;
  }
  bf16_t* sAb = &sA[0][0];
  bf16_t* sBb = &sB[0][0];

  auto STAGE = [&](int buf, int kt) {
    const int kk = kt * BKG;
    const int boff = buf * (128 * BKG);
    glds16(pA0 + kk, sAb + boff + (c0    ) * 512);
    glds16(pA1 + kk, sAb + boff + (c0 + 1) * 512);
    glds16(pB0 + kk, sBb + boff + (c0    ) * 512);
    glds16(pB1 + kk, sBb + boff + (c0 + 1) * 512);
  };

  f32x4 acc[4][4];
#pragma unroll
  for (int mi = 0; mi < 4; mi++)
#pragma unroll
    for (int ni = 0; ni < 4; ni++) acc[mi][ni] = (f32x4)(0.f);

  const int wr = wave >> 1, wc = wave & 1;
  const int lr = lane & 15, lg = lane >> 4;
  const int NKI = K / BKG;

  STAGE(0, 0);
  __syncthreads();
  int cur = 0;
  for (int kt = 0; kt < NKI; ++kt) {
    if (kt + 1 < NKI) STAGE(cur ^ 1, kt + 1);
    const bf16_t* sa = sAb + cur * (128 * BKG);
    const bf16_t* sb = sBb + cur * (128 * BKG);
    bf16x8 af[4];
#pragma unroll
    for (int mi = 0; mi < 4; mi++)
      af[mi] = *(const bf16x8*)&sa[(wr * 64 + mi * 16 + lr) * BKG + lg * 8];
#pragma unroll
    for (int ni = 0; ni < 4; ni++) {
      bf16x8 bfrag = *(const bf16x8*)&sb[(wc * 64 + ni * 16 + lr) * BKG + lg * 8];
#pragma unroll
      for (int mi = 0; mi < 4; mi++)
        acc[mi][ni] = __builtin_amdgcn_mfma_f32_16x16x32_bf16(af[mi], bfrag, acc[mi][ni], 0, 0, 0);
    }
    __syncthreads();
    cur ^= 1;
  }

#pragma unroll
  for (int mi = 0; mi < 4; mi++) {
#pragma unroll
    for (int j = 0; j < 4; j++) {
      int rl = wr * 64 + mi * 16 + lg * 4 + j;
      int grow = row0 + rl;
      if (GATHER && grow >= cnt) continue;
      if (GATHER) {
        int slot = slot0 + grow;
        int tokn = tok_idx[slot];
        float w = tok_w[slot];
#pragma unroll
        for (int ni = 0; ni < 4; ni++) {
          int col = n0 + wc * 64 + ni * 16 + lr;
          atomicAdd(&out[(size_t)tokn * N + col], w * acc[mi][ni][j]);
        }
      } else {
#pragma unroll
        for (int ni = 0; ni < 4; ni++) {
          int col = n0 + wc * 64 + ni * 16 + lr;
          out[(size_t)grow * N + col] = acc[mi][ni][j] + bias[col];
        }
      }
    }
  }
}

extern "C" void kernel_launch(void* const* d_in, const int* in_sizes, int n_in,
                              void* d_out, int out_size, void* d_ws, size_t ws_size,
                              hipStream_t stream) {
  const float* x_f  = (const float*)d_in[0];
  const float* rw   = (const float*)d_in[1];
  const float* gate = (const float*)d_in[2];
  const float* up   = (const float*)d_in[3];
  const float* down = (const float*)d_in[4];
  const float* sgw  = (const float*)d_in[5];
  const float* sgb  = (const float*)d_in[6];
  const float* suw  = (const float*)d_in[7];
  const float* sub  = (const float*)d_in[8];
  const float* sdw  = (const float*)d_in[9];
  const float* sdb  = (const float*)d_in[10];
  float* out = (float*)d_out;

  char* ws = (char*)d_ws;
  size_t off = 0;
  auto alloc = [&](size_t bytes) {
    char* p = ws + off;
    off += (bytes + 255) & ~(size_t)255;
    return p;
  };
  bf16_t* xb    = (bf16_t*)alloc((size_t)T_TOK * HDIM * 2);
  bf16_t* gT    = (bf16_t*)alloc((size_t)NEXP * IDIM * HDIM * 2);
  bf16_t* uT    = (bf16_t*)alloc((size_t)NEXP * IDIM * HDIM * 2);
  bf16_t* dT    = (bf16_t*)alloc((size_t)NEXP * HDIM * IDIM * 2);
  bf16_t* sgT   = (bf16_t*)alloc((size_t)SIDIM * HDIM * 2);
  bf16_t* suT   = (bf16_t*)alloc((size_t)SIDIM * HDIM * 2);
  bf16_t* sdT   = (bf16_t*)alloc((size_t)HDIM * SIDIM * 2);
  bf16_t* hid_r = (bf16_t*)alloc((size_t)T_TOK * 2 * IDIM * 2);
  bf16_t* hid_s = (bf16_t*)alloc((size_t)T_TOK * SIDIM * 2);
  int*    meta  = (int*)alloc(128);
  int*    tok_idx = (int*)alloc(8192 * 4);
  float*  tok_w   = (float*)alloc(8192 * 4);
  int*    tk_i    = (int*)alloc((size_t)T_TOK * 2 * 4);
  float*  tk_w2   = (float*)alloc((size_t)T_TOK * 2 * 4);

  int* counts = meta;
  int* cursor = meta + 8;
  int* offs   = meta + 16;

  hipMemsetAsync(meta, 0, 128, stream);

  cvt_x_kernel<<<(T_TOK * HDIM / 4) / 256, 256, 0, stream>>>(
      (const float4*)x_f, (bf16x4*)xb, T_TOK * HDIM / 4);

  tcvt_kernel<<<dim3(IDIM / 64, HDIM / 64, NEXP), 256, 0, stream>>>(gate, gT, HDIM, IDIM);
  tcvt_kernel<<<dim3(IDIM / 64, HDIM / 64, NEXP), 256, 0, stream>>>(up,   uT, HDIM, IDIM);
  tcvt_kernel<<<dim3(HDIM / 64, IDIM / 64, NEXP), 256, 0, stream>>>(down, dT, IDIM, HDIM);
  tcvt_kernel<<<dim3(SIDIM / 64, HDIM / 64, 1), 256, 0, stream>>>(sgw, sgT, HDIM, SIDIM);
  tcvt_kernel<<<dim3(SIDIM / 64, HDIM / 64, 1), 256, 0, stream>>>(suw, suT, HDIM, SIDIM);
  tcvt_kernel<<<dim3(HDIM / 64, SIDIM / 64, 1), 256, 0, stream>>>(sdw, sdT, SIDIM, HDIM);

  router_kernel<<<T_TOK / 4, 256, 0, stream>>>(x_f, rw, tk_i, tk_w2, counts);
  offs_kernel<<<1, 64, 0, stream>>>(counts, offs);
  scatter_kernel<<<T_TOK / 256, 256, 0, stream>>>(tk_i, tk_w2, offs, cursor, tok_idx, tok_w);

  gateup_kernel<true><<<dim3(IDIM / 128, T_TOK / 128, NEXP), 256, 0, stream>>>(
      xb, gT, uT, nullptr, nullptr, offs, tok_idx, hid_r, IDIM, HDIM);
  gateup_kernel<false><<<dim3(SIDIM / 128, T_TOK / 128, 1), 256, 0, stream>>>(
      xb, sgT, suT, sgb, sub, nullptr, nullptr, hid_s, SIDIM, HDIM);

  down_kernel<false><<<dim3(HDIM / 128, T_TOK / 128, 1), 256, 0, stream>>>(
      hid_s, sdT, sdb, nullptr, nullptr, nullptr, out, SIDIM);
  down_kernel<true><<<dim3(HDIM / 128, T_TOK / 128, NEXP), 256, 0, stream>>>(
      hid_r, dT, nullptr, offs, tok_idx, tok_w, out, IDIM);
}

// Round 3
// 716.034 us; speedup vs baseline: 1.2990x; 1.2990x over previous
//
#include <hip/hip_runtime.h>
#include <hip/hip_bf16.h>
#include <stdint.h>

#define T_TOK 4096
#define HDIM  2048
#define IDIM  1408
#define NEXP  8
#define SIDIM 2816
#define MAXMT 39   // max 256-row tiles over 8192 slots + 7 residuals

typedef __bf16 bf16_t;
typedef __bf16 bf16x8 __attribute__((ext_vector_type(8)));
typedef __bf16 bf16x4 __attribute__((ext_vector_type(4)));
typedef float  f32x4  __attribute__((ext_vector_type(4)));

typedef uint32_t __attribute__((address_space(3))) lds_u32;
typedef uint32_t __attribute__((address_space(1))) glb_u32;

__device__ __forceinline__ void glds16(const bf16_t* g, const char* l) {
  __builtin_amdgcn_global_load_lds((const glb_u32*)g, (lds_u32*)l, 16, 0, 0);
}

__device__ __forceinline__ void bar() {
  asm volatile("" ::: "memory");
  __builtin_amdgcn_s_barrier();
  asm volatile("" ::: "memory");
}
#define VMW asm volatile("s_waitcnt vmcnt(4)" ::: "memory")

// m204 bijective XCD swizzle
__device__ __forceinline__ int xcd_swz(int orig, int nwg) {
  int q = nwg >> 3, r = nwg & 7;
  int x = orig & 7, i = orig >> 3;
  return (x < r ? x * (q + 1) : r * (q + 1) + (x - r) * q) + i;
}

// ---------------- convert x (f32 -> bf16) ----------------
__global__ void cvt_x_kernel(const float4* __restrict__ in, bf16x4* __restrict__ out, int n4) {
  int i = blockIdx.x * 256 + threadIdx.x;
  if (i >= n4) return;
  float4 v = in[i];
  bf16x4 o;
  o[0] = (bf16_t)v.x; o[1] = (bf16_t)v.y; o[2] = (bf16_t)v.z; o[3] = (bf16_t)v.w;
  out[i] = o;
}

// ---------------- transpose+convert: f32 [R][C] -> bf16 [C][R], z-batched ----------------
__global__ void tcvt_kernel(const float* __restrict__ in, bf16_t* __restrict__ out, int R, int C) {
  in  += (size_t)blockIdx.z * R * C;
  out += (size_t)blockIdx.z * R * C;
  __shared__ bf16_t tb[64][72];
  const int r0 = blockIdx.y * 64, c0 = blockIdx.x * 64;
  const int tid = threadIdx.x;
  const int cf4 = tid & 15, rr = tid >> 4;
#pragma unroll
  for (int s = 0; s < 4; ++s) {
    int r = rr + 16 * s;
    float4 v = *(const float4*)(in + (size_t)(r0 + r) * C + c0 + cf4 * 4);
    tb[cf4 * 4 + 0][r] = (bf16_t)v.x;
    tb[cf4 * 4 + 1][r] = (bf16_t)v.y;
    tb[cf4 * 4 + 2][r] = (bf16_t)v.z;
    tb[cf4 * 4 + 3][r] = (bf16_t)v.w;
  }
  __syncthreads();
  const int c = tid >> 2, rb = (tid & 3) * 16;
  bf16x8 w0 = *(const bf16x8*)&tb[c][rb];
  bf16x8 w1 = *(const bf16x8*)&tb[c][rb + 8];
  bf16_t* op = out + (size_t)(c0 + c) * R + r0 + rb;
  *(bf16x8*)op = w0;
  *(bf16x8*)(op + 8) = w1;
}

// transpose+convert with gate/up interleave: out row n' = (c>>7)*256 + which*128 + (c&127)
__global__ void tcvt_gu_kernel(const float* __restrict__ in, bf16_t* __restrict__ out,
                               int R, int C, int which) {
  in  += (size_t)blockIdx.z * R * C;
  out += (size_t)blockIdx.z * (2 * C) * R;
  __shared__ bf16_t tb[64][72];
  const int r0 = blockIdx.y * 64, c0 = blockIdx.x * 64;
  const int tid = threadIdx.x;
  const int cf4 = tid & 15, rr = tid >> 4;
#pragma unroll
  for (int s = 0; s < 4; ++s) {
    int r = rr + 16 * s;
    float4 v = *(const float4*)(in + (size_t)(r0 + r) * C + c0 + cf4 * 4);
    tb[cf4 * 4 + 0][r] = (bf16_t)v.x;
    tb[cf4 * 4 + 1][r] = (bf16_t)v.y;
    tb[cf4 * 4 + 2][r] = (bf16_t)v.z;
    tb[cf4 * 4 + 3][r] = (bf16_t)v.w;
  }
  __syncthreads();
  const int c = tid >> 2, rb = (tid & 3) * 16;
  bf16x8 w0 = *(const bf16x8*)&tb[c][rb];
  bf16x8 w1 = *(const bf16x8*)&tb[c][rb + 8];
  int cg = c0 + c;
  int nprime = ((cg >> 7) << 8) + which * 128 + (cg & 127);
  bf16_t* op = out + (size_t)nprime * R + r0 + rb;
  *(bf16x8*)op = w0;
  *(bf16x8*)(op + 8) = w1;
}

// ---------------- router ----------------
__global__ void router_kernel(const float* __restrict__ x, const float* __restrict__ rw,
                              int* __restrict__ tk_i, float* __restrict__ tk_w,
                              int* __restrict__ counts) {
  int gtid = blockIdx.x * 256 + threadIdx.x;
  int t = gtid >> 6, lane = gtid & 63;
  const float4* xr = (const float4*)(x + (size_t)t * HDIM);
  float acc[NEXP];
#pragma unroll
  for (int e = 0; e < NEXP; e++) acc[e] = 0.f;
  for (int i = lane; i < HDIM / 4; i += 64) {
    float4 xv = xr[i];
#pragma unroll
    for (int e = 0; e < NEXP; e++) {
      float4 wv = ((const float4*)(rw + e * HDIM))[i];
      acc[e] += xv.x * wv.x + xv.y * wv.y + xv.z * wv.z + xv.w * wv.w;
    }
  }
#pragma unroll
  for (int e = 0; e < NEXP; e++)
#pragma unroll
    for (int off = 32; off; off >>= 1) acc[e] += __shfl_down(acc[e], off);
  if (lane == 0) {
    int i1 = 0; float m1 = acc[0];
#pragma unroll
    for (int e = 1; e < NEXP; e++) if (acc[e] > m1) { m1 = acc[e]; i1 = e; }
    int i2 = -1; float m2 = -1e30f;
#pragma unroll
    for (int e = 0; e < NEXP; e++) if (e != i1 && acc[e] > m2) { m2 = acc[e]; i2 = e; }
    float w1 = 1.f / (1.f + __expf(m2 - m1));
    tk_i[t * 2] = i1; tk_i[t * 2 + 1] = i2;
    tk_w[t * 2] = w1; tk_w[t * 2 + 1] = 1.f - w1;
    atomicAdd(&counts[i1], 1); atomicAdd(&counts[i2], 1);
  }
}

// meta layout: [0..7] counts, [8..15] cursor, [16..24] offs, [25] nmt,
//              [32..70] tile->expert, [80..118] tile->row0
__global__ void offs_kernel(int* __restrict__ meta) {
  if (threadIdx.x == 0 && blockIdx.x == 0) {
    int o = 0;
    for (int e = 0; e < NEXP; e++) { meta[16 + e] = o; o += meta[e]; }
    meta[24] = o;
    int nmt = 0;
    for (int e = 0; e < NEXP; e++) {
      int c = meta[e];
      int nt = (c + 255) >> 8;
      for (int i = 0; i < nt; i++) { meta[32 + nmt] = e; meta[80 + nmt] = i * 256; nmt++; }
    }
    meta[25] = nmt;
  }
}

__global__ void scatter_kernel(const int* __restrict__ tk_i, const float* __restrict__ tk_w,
                               int* __restrict__ meta,
                               int* __restrict__ tok_idx, float* __restrict__ tok_w) {
  int t = blockIdx.x * 256 + threadIdx.x;
  if (t >= T_TOK) return;
#pragma unroll
  for (int k = 0; k < 2; k++) {
    int e = tk_i[t * 2 + k];
    int pos = meta[16 + e] + atomicAdd(&meta[8 + e], 1);
    tok_idx[pos] = t; tok_w[pos] = tk_w[t * 2 + k];
  }
}

// ---------------- 8-phase 256x256 GEMM (T2 swizzle + T3/T4 counted vmcnt + T5 setprio) ----
// A:[rows][K] bf16 (gathered if GATHER), B:[N'][K] bf16 (per-expert if GATHER).
// GATEUP: B is gate/up interleaved (256-tile = [gate128|up128]); silu(g)*u -> Hout bf16.
// !GATEUP: down-proj; GATHER -> atomicAdd(out, w*acc), else out = acc + dbias.
template <bool GATHER, bool GATEUP>
__global__ __launch_bounds__(512, 2)
void gemm8p(const bf16_t* __restrict__ A, const bf16_t* __restrict__ B, int K,
            const int* __restrict__ meta, const int* __restrict__ tok_idx,
            const float* __restrict__ tok_w, const float* __restrict__ bg,
            const float* __restrict__ bu, bf16_t* __restrict__ Hout, int HN,
            float* __restrict__ out, const float* __restrict__ dbias) {
  __shared__ __align__(16) char smem[131072];  // A: 2x32KB @0, B: 2x32KB @65536

  const int NX = gridDim.x, NY = gridDim.y;
  const int l = blockIdx.x + NX * blockIdx.y;
  const int s = xcd_swz(l, NX * NY);
  const int yt = s % NY, xt = s / NY;   // row-fastest: consecutive s share B panel

  int row0, cnt, slot0;
  const bf16_t* Bexp;
  if (GATHER) {
    int nmt = meta[25];
    if (yt >= nmt) return;
    int e = meta[32 + yt];
    row0 = meta[80 + yt];
    slot0 = meta[16 + e];
    cnt = meta[16 + e + 1] - slot0;
    Bexp = B + (size_t)e * (size_t)(GATEUP ? 2 * IDIM : HDIM) * K;
  } else { row0 = yt * 256; cnt = T_TOK; slot0 = 0; Bexp = B; }
  const int n0 = xt * 256;

  const int t = threadIdx.x;
  const int lane = t & 63, wid = t >> 6;
  const int wr = wid >> 2, wc = wid & 3;
  const int lr = lane & 15, lg = lane >> 4;

  // staging: 4 A-granules + 4 B-granules per thread per K-tile (16B each)
  const bf16_t* pA[4]; const bf16_t* pB[4]; int dG[4];
#pragma unroll
  for (int j = 0; j < 4; ++j) {
    int g = j * 512 + t;
    int r = g >> 3;
    int c16 = (g & 7) ^ (r & 7);          // inverse-swizzled global source (rule 21)
    dG[j] = g * 16;                        // linear LDS dest byte
    int arow;
    if (GATHER) {
      int rr = row0 + r; if (rr >= cnt) rr = cnt - 1;
      arow = GATEUP ? tok_idx[slot0 + rr] : (slot0 + rr);
    } else arow = row0 + r;
    pA[j] = A + (size_t)arow * K + c16 * 8;
    pB[j] = Bexp + (size_t)(n0 + r) * K + c16 * 8;
  }

  // swizzled ds_read column offsets (row&7 == lr&7 for all frag rows)
  const int cswz0 = ((lg) ^ (lr & 7)) * 16;
  const int cswz1 = ((4 + lg) ^ (lr & 7)) * 16;
  const int aRowB = (wr * 128 + lr) * 128;
  const int bRowB = (wc * 64 + lr) * 128 + 65536;

  f32x4 acc[8][4];
#pragma unroll
  for (int mi = 0; mi < 8; ++mi)
#pragma unroll
    for (int ni = 0; ni < 4; ++ni) acc[mi][ni] = (f32x4)(0.f);

  bf16x8 aL[4][2], aH[4][2], bL[2][2], bH[2][2];
  const int NKT = K >> 6;

#define ST_A(BUFO, KT, JH) { \
    glds16(pA[(JH)*2]   + (KT)*64, smem + (BUFO) + dG[(JH)*2]); \
    glds16(pA[(JH)*2+1] + (KT)*64, smem + (BUFO) + dG[(JH)*2+1]); }
#define ST_B(BUFO, KT, JH) { \
    glds16(pB[(JH)*2]   + (KT)*64, smem + 65536 + (BUFO) + dG[(JH)*2]); \
    glds16(pB[(JH)*2+1] + (KT)*64, smem + 65536 + (BUFO) + dG[(JH)*2+1]); }
#define RD_A(af, BUFO, MIH) { \
    _Pragma("unroll") for (int mi = 0; mi < 4; ++mi) { \
      af[mi][0] = *(const bf16x8*)(smem + (BUFO) + aRowB + (MIH)*8192 + mi*2048 + cswz0); \
      af[mi][1] = *(const bf16x8*)(smem + (BUFO) + aRowB + (MIH)*8192 + mi*2048 + cswz1); } }
#define RD_B(bf, BUFO, NIH) { \
    _Pragma("unroll") for (int ni = 0; ni < 2; ++ni) { \
      bf[ni][0] = *(const bf16x8*)(smem + (BUFO) + bRowB + (NIH)*4096 + ni*2048 + cswz0); \
      bf[ni][1] = *(const bf16x8*)(smem + (BUFO) + bRowB + (NIH)*4096 + ni*2048 + cswz1); } }
#define MMQ(af, bf, MO, NO) { \
    __builtin_amdgcn_s_setprio(1); \
    _Pragma("unroll") for (int ni = 0; ni < 2; ++ni) \
    _Pragma("unroll") for (int mi = 0; mi < 4; ++mi) { \
      acc[(MO)+mi][(NO)+ni] = __builtin_amdgcn_mfma_f32_16x16x32_bf16(af[mi][0], bf[ni][0], acc[(MO)+mi][(NO)+ni], 0, 0, 0); \
      acc[(MO)+mi][(NO)+ni] = __builtin_amdgcn_mfma_f32_16x16x32_bf16(af[mi][1], bf[ni][1], acc[(MO)+mi][(NO)+ni], 0, 0, 0); } \
    __builtin_amdgcn_s_setprio(0); }

// one K-tile: 4 phases; stage FIFO per tile = B(t+1)h0, B(t+1)h1, A(t+2)h0, A(t+2)h1
// -> vmcnt(4) at tile end leaves only A(t+2) outstanding.
#define KTILE(KT, BO, NBO) { \
    RD_A(aL, BO, 0); RD_B(bL, BO, 0); \
    if ((KT) + 1 < NKT) ST_B(NBO, (KT) + 1, 0); \
    bar(); MMQ(aL, bL, 0, 0); bar(); \
    RD_A(aH, BO, 1); \
    if ((KT) + 1 < NKT) ST_B(NBO, (KT) + 1, 1); \
    bar(); MMQ(aH, bL, 4, 0); bar(); \
    RD_B(bH, BO, 1); \
    if ((KT) + 2 < NKT) ST_A(BO, (KT) + 2, 0); \
    bar(); MMQ(aH, bH, 4, 2); bar(); \
    if ((KT) + 2 < NKT) ST_A(BO, (KT) + 2, 1); \
    bar(); MMQ(aL, bH, 0, 2); \
    VMW; bar(); }

  // prologue: A(t0), B(t0), A(t1); wait t0 landed (vmcnt(4) leaves A(t1) in flight)
  ST_A(0, 0, 0); ST_A(0, 0, 1);
  ST_B(0, 0, 0); ST_B(0, 0, 1);
  ST_A(32768, 1, 0); ST_A(32768, 1, 1);
  VMW; bar();

  for (int kt = 0; kt < NKT; kt += 2) {
    KTILE(kt, 0, 32768);
    KTILE(kt + 1, 32768, 0);
  }

  // ---------------- epilogues ----------------
  if (GATEUP) {
    float* lf = (float*)smem;             // [256 rows][128 cols] f32 = 128KB
    if (wc >= 2) {
#pragma unroll
      for (int mi = 0; mi < 8; ++mi)
#pragma unroll
        for (int ni = 0; ni < 4; ++ni)
#pragma unroll
          for (int j = 0; j < 4; ++j) {
            int row = wr * 128 + mi * 16 + lg * 4 + j;
            int col = (wc - 2) * 64 + ni * 16 + lr;
            float u = acc[mi][ni][j];
            if (!GATHER) u += bu[xt * 128 + col];
            lf[row * 128 + col] = u;
          }
    }
    __syncthreads();
    if (wc < 2) {
#pragma unroll
      for (int mi = 0; mi < 8; ++mi)
#pragma unroll
        for (int ni = 0; ni < 4; ++ni)
#pragma unroll
          for (int j = 0; j < 4; ++j) {
            int row = wr * 128 + mi * 16 + lg * 4 + j;
            int grow = row0 + row;
            if (GATHER && grow >= cnt) continue;
            int col = wc * 64 + ni * 16 + lr;
            float g = acc[mi][ni][j];
            if (!GATHER) g += bg[xt * 128 + col];
            float u = lf[row * 128 + col];
            float h = (g / (1.f + __expf(-g))) * u;
            size_t orow = GATHER ? (size_t)(slot0 + grow) : (size_t)grow;
            Hout[orow * HN + xt * 128 + col] = (bf16_t)h;
          }
    }
  } else {
#pragma unroll
    for (int mi = 0; mi < 8; ++mi)
#pragma unroll
      for (int j = 0; j < 4; ++j) {
        int row = wr * 128 + mi * 16 + lg * 4 + j;
        int grow = row0 + row;
        if (GATHER) {
          if (grow >= cnt) continue;
          int slot = slot0 + grow;
          int tk = tok_idx[slot];
          float w = tok_w[slot];
#pragma unroll
          for (int ni = 0; ni < 4; ++ni) {
            int col = n0 + wc * 64 + ni * 16 + lr;
            atomicAdd(&out[(size_t)tk * HDIM + col], w * acc[mi][ni][j]);
          }
        } else {
#pragma unroll
          for (int ni = 0; ni < 4; ++ni) {
            int col = n0 + wc * 64 + ni * 16 + lr;
            out[(size_t)grow * HDIM + col] = acc[mi][ni][j] + dbias[col];
          }
        }
      }
  }
#undef ST_A
#undef ST_B
#undef RD_A
#undef RD_B
#undef MMQ
#undef KTILE
}

extern "C" void kernel_launch(void* const* d_in, const int* in_sizes, int n_in,
                              void* d_out, int out_size, void* d_ws, size_t ws_size,
                              hipStream_t stream) {
  const float* x_f  = (const float*)d_in[0];
  const float* rw   = (const float*)d_in[1];
  const float* gate = (const float*)d_in[2];
  const float* up   = (const float*)d_in[3];
  const float* down = (const float*)d_in[4];
  const float* sgw  = (const float*)d_in[5];
  const float* sgb  = (const float*)d_in[6];
  const float* suw  = (const float*)d_in[7];
  const float* sub  = (const float*)d_in[8];
  const float* sdw  = (const float*)d_in[9];
  const float* sdb  = (const float*)d_in[10];
  float* out = (float*)d_out;

  char* ws = (char*)d_ws;
  size_t off = 0;
  auto alloc = [&](size_t bytes) {
    char* p = ws + off;
    off += (bytes + 255) & ~(size_t)255;
    return p;
  };
  bf16_t* xb    = (bf16_t*)alloc((size_t)T_TOK * HDIM * 2);
  bf16_t* BguR  = (bf16_t*)alloc((size_t)NEXP * 2 * IDIM * HDIM * 2);   // [e][2816][2048]
  bf16_t* BguS  = (bf16_t*)alloc((size_t)2 * SIDIM * HDIM * 2);         // [5632][2048]
  bf16_t* dT    = (bf16_t*)alloc((size_t)NEXP * HDIM * IDIM * 2);       // [e][2048][1408]
  bf16_t* sdT   = (bf16_t*)alloc((size_t)HDIM * SIDIM * 2);             // [2048][2816]
  bf16_t* hid_r = (bf16_t*)alloc((size_t)T_TOK * 2 * IDIM * 2);
  bf16_t* hid_s = (bf16_t*)alloc((size_t)T_TOK * SIDIM * 2);
  int*    meta  = (int*)alloc(1024);
  int*    tok_idx = (int*)alloc(8192 * 4);
  float*  tok_w   = (float*)alloc(8192 * 4);
  int*    tk_i    = (int*)alloc((size_t)T_TOK * 2 * 4);
  float*  tk_w2   = (float*)alloc((size_t)T_TOK * 2 * 4);

  hipMemsetAsync(meta, 0, 64, stream);  // counts + cursor

  cvt_x_kernel<<<(T_TOK * HDIM / 4) / 256, 256, 0, stream>>>(
      (const float4*)x_f, (bf16x4*)xb, T_TOK * HDIM / 4);

  tcvt_gu_kernel<<<dim3(IDIM / 64, HDIM / 64, NEXP), 256, 0, stream>>>(gate, BguR, HDIM, IDIM, 0);
  tcvt_gu_kernel<<<dim3(IDIM / 64, HDIM / 64, NEXP), 256, 0, stream>>>(up,   BguR, HDIM, IDIM, 1);
  tcvt_gu_kernel<<<dim3(SIDIM / 64, HDIM / 64, 1), 256, 0, stream>>>(sgw, BguS, HDIM, SIDIM, 0);
  tcvt_gu_kernel<<<dim3(SIDIM / 64, HDIM / 64, 1), 256, 0, stream>>>(suw, BguS, HDIM, SIDIM, 1);
  tcvt_kernel<<<dim3(HDIM / 64, IDIM / 64, NEXP), 256, 0, stream>>>(down, dT, IDIM, HDIM);
  tcvt_kernel<<<dim3(HDIM / 64, SIDIM / 64, 1), 256, 0, stream>>>(sdw, sdT, SIDIM, HDIM);

  router_kernel<<<T_TOK / 4, 256, 0, stream>>>(x_f, rw, tk_i, tk_w2, meta);
  offs_kernel<<<1, 64, 0, stream>>>(meta);
  scatter_kernel<<<T_TOK / 256, 256, 0, stream>>>(tk_i, tk_w2, meta, tok_idx, tok_w);

  // routed gate/up (gathered A, interleaved B) -> hid_r [8192][1408]
  gemm8p<true, true><<<dim3((2 * IDIM) / 256, MAXMT), 512, 0, stream>>>(
      xb, BguR, HDIM, meta, tok_idx, tok_w, nullptr, nullptr, hid_r, IDIM, nullptr, nullptr);
  // shared gate/up -> hid_s [4096][2816]
  gemm8p<false, true><<<dim3((2 * SIDIM) / 256, T_TOK / 256), 512, 0, stream>>>(
      xb, BguS, HDIM, meta, nullptr, nullptr, sgb, sub, hid_s, SIDIM, nullptr, nullptr);
  // shared down WRITES out (+bias) first
  gemm8p<false, false><<<dim3(HDIM / 256, T_TOK / 256), 512, 0, stream>>>(
      hid_s, sdT, SIDIM, meta, nullptr, nullptr, nullptr, nullptr, nullptr, 0, out, sdb);
  // routed down atomically accumulates w * acc
  gemm8p<true, false><<<dim3(HDIM / 256, MAXMT), 512, 0, stream>>>(
      hid_r, dT, IDIM, meta, tok_idx, tok_w, nullptr, nullptr, nullptr, 0, out, nullptr);
}

// Round 5
// 621.962 us; speedup vs baseline: 1.4955x; 1.1513x over previous
//
#include <hip/hip_runtime.h>
#include <hip/hip_bf16.h>
#include <stdint.h>

#define T_TOK 4096
#define HDIM  2048
#define IDIM  1408
#define NEXP  8
#define SIDIM 2816
#define GU_CAP 781   // 39*11 + 22*16
#define DN_CAP 568   // 39*8 + 2*8*16

typedef __bf16 bf16_t;
typedef __bf16 bf16x8 __attribute__((ext_vector_type(8)));
typedef __bf16 bf16x4 __attribute__((ext_vector_type(4)));
typedef float  f32x4  __attribute__((ext_vector_type(4)));

typedef uint32_t __attribute__((address_space(3))) lds_u32;
typedef uint32_t __attribute__((address_space(1))) glb_u32;

__device__ __forceinline__ void glds16(const bf16_t* g, const char* l) {
  __builtin_amdgcn_global_load_lds((const glb_u32*)g, (lds_u32*)l, 16, 0, 0);
}

__device__ __forceinline__ void bar() {
  asm volatile("" ::: "memory");
  __builtin_amdgcn_s_barrier();
  asm volatile("" ::: "memory");
}
// steady-state: 12 staging ops in flight, wait 8 oldest (A(t+1),B(t+1)), keep A(t+2)
#define VMW4 asm volatile("s_waitcnt vmcnt(4)" ::: "memory")
// K-loop tail: fewer ops were issued -> must drain fully or next tile races the DMA
#define VMW0 asm volatile("s_waitcnt vmcnt(0)" ::: "memory")

// m204 bijective XCD swizzle
__device__ __forceinline__ int xcd_swz(int orig, int nwg) {
  int q = nwg >> 3, r = nwg & 7;
  int x = orig & 7, i = orig >> 3;
  return (x < r ? x * (q + 1) : r * (q + 1) + (x - r) * q) + i;
}

// ---------------- convert x (f32 -> bf16) ----------------
__global__ void cvt_x_kernel(const float4* __restrict__ in, bf16x4* __restrict__ out, int n4) {
  int i = blockIdx.x * 256 + threadIdx.x;
  if (i >= n4) return;
  float4 v = in[i];
  bf16x4 o;
  o[0] = (bf16_t)v.x; o[1] = (bf16_t)v.y; o[2] = (bf16_t)v.z; o[3] = (bf16_t)v.w;
  out[i] = o;
}

// ---------------- transpose+convert: f32 [R][C] -> bf16 [C][R], z-batched ----------------
__global__ void tcvt_kernel(const float* __restrict__ in, bf16_t* __restrict__ out, int R, int C) {
  in  += (size_t)blockIdx.z * R * C;
  out += (size_t)blockIdx.z * R * C;
  __shared__ bf16_t tb[64][72];
  const int r0 = blockIdx.y * 64, c0 = blockIdx.x * 64;
  const int tid = threadIdx.x;
  const int cf4 = tid & 15, rr = tid >> 4;
#pragma unroll
  for (int s = 0; s < 4; ++s) {
    int r = rr + 16 * s;
    float4 v = *(const float4*)(in + (size_t)(r0 + r) * C + c0 + cf4 * 4);
    tb[cf4 * 4 + 0][r] = (bf16_t)v.x;
    tb[cf4 * 4 + 1][r] = (bf16_t)v.y;
    tb[cf4 * 4 + 2][r] = (bf16_t)v.z;
    tb[cf4 * 4 + 3][r] = (bf16_t)v.w;
  }
  __syncthreads();
  const int c = tid >> 2, rb = (tid & 3) * 16;
  bf16x8 w0 = *(const bf16x8*)&tb[c][rb];
  bf16x8 w1 = *(const bf16x8*)&tb[c][rb + 8];
  bf16_t* op = out + (size_t)(c0 + c) * R + r0 + rb;
  *(bf16x8*)op = w0;
  *(bf16x8*)(op + 8) = w1;
}

// transpose+convert, gate/up interleaved at 16-col granularity:
// out row n' = (c>>4)*32 + which*16 + (c&15)   (in-register SwiGLU pairing)
__global__ void tcvt_gu_kernel(const float* __restrict__ in, bf16_t* __restrict__ out,
                               int R, int C, int which) {
  in  += (size_t)blockIdx.z * R * C;
  out += (size_t)blockIdx.z * (2 * C) * R;
  __shared__ bf16_t tb[64][72];
  const int r0 = blockIdx.y * 64, c0 = blockIdx.x * 64;
  const int tid = threadIdx.x;
  const int cf4 = tid & 15, rr = tid >> 4;
#pragma unroll
  for (int s = 0; s < 4; ++s) {
    int r = rr + 16 * s;
    float4 v = *(const float4*)(in + (size_t)(r0 + r) * C + c0 + cf4 * 4);
    tb[cf4 * 4 + 0][r] = (bf16_t)v.x;
    tb[cf4 * 4 + 1][r] = (bf16_t)v.y;
    tb[cf4 * 4 + 2][r] = (bf16_t)v.z;
    tb[cf4 * 4 + 3][r] = (bf16_t)v.w;
  }
  __syncthreads();
  const int c = tid >> 2, rb = (tid & 3) * 16;
  bf16x8 w0 = *(const bf16x8*)&tb[c][rb];
  bf16x8 w1 = *(const bf16x8*)&tb[c][rb + 8];
  int cg = c0 + c;
  int nprime = ((cg >> 4) << 5) + which * 16 + (cg & 15);
  bf16_t* op = out + (size_t)nprime * R + r0 + rb;
  *(bf16x8*)op = w0;
  *(bf16x8*)(op + 8) = w1;
}

// ---------------- router ----------------
__global__ void router_kernel(const float* __restrict__ x, const float* __restrict__ rw,
                              int* __restrict__ tk_i, float* __restrict__ tk_w,
                              int* __restrict__ counts) {
  int gtid = blockIdx.x * 256 + threadIdx.x;
  int t = gtid >> 6, lane = gtid & 63;
  const float4* xr = (const float4*)(x + (size_t)t * HDIM);
  float acc[NEXP];
#pragma unroll
  for (int e = 0; e < NEXP; e++) acc[e] = 0.f;
  for (int i = lane; i < HDIM / 4; i += 64) {
    float4 xv = xr[i];
#pragma unroll
    for (int e = 0; e < NEXP; e++) {
      float4 wv = ((const float4*)(rw + e * HDIM))[i];
      acc[e] += xv.x * wv.x + xv.y * wv.y + xv.z * wv.z + xv.w * wv.w;
    }
  }
#pragma unroll
  for (int e = 0; e < NEXP; e++)
#pragma unroll
    for (int off = 32; off; off >>= 1) acc[e] += __shfl_down(acc[e], off);
  if (lane == 0) {
    int i1 = 0; float m1 = acc[0];
#pragma unroll
    for (int e = 1; e < NEXP; e++) if (acc[e] > m1) { m1 = acc[e]; i1 = e; }
    int i2 = -1; float m2 = -1e30f;
#pragma unroll
    for (int e = 0; e < NEXP; e++) if (e != i1 && acc[e] > m2) { m2 = acc[e]; i2 = e; }
    float w1 = 1.f / (1.f + __expf(m2 - m1));
    tk_i[t * 2] = i1; tk_i[t * 2 + 1] = i2;
    tk_w[t * 2] = w1; tk_w[t * 2 + 1] = 1.f - w1;
    atomicAdd(&counts[i1], 1); atomicAdd(&counts[i2], 1);
  }
}

// meta: [0..7] counts, [8..15] cursor, [16..24] offs, [25] nmt, [26] ntiles_gu,
// [27] ntiles_dn, [32..70] tile_e, [80..118] tile_row0,
// [128..] gateup table (int4), [3328..] down table (int4)
__global__ void build_kernel(int* __restrict__ meta) {
  __shared__ int snmt;
  if (threadIdx.x == 0) {
    int o = 0;
    for (int e = 0; e < NEXP; e++) { meta[16 + e] = o; o += meta[e]; }
    meta[24] = o;
    int nmt = 0;
    for (int e = 0; e < NEXP; e++) {
      int nt = (meta[e] + 255) >> 8;
      for (int i = 0; i < nt; i++) { meta[32 + nmt] = e; meta[80 + nmt] = i << 8; nmt++; }
    }
    meta[25] = nmt;
    meta[26] = nmt * 11 + 352;
    meta[27] = nmt * 8 + 256;
    snmt = nmt;
  }
  __syncthreads();
  const int nmt = snmt;
  int4* gt = (int4*)(meta + 128);
  const int ng = nmt * 11 + 352;
  for (int i = threadIdx.x; i < ng; i += 256) {
    int4 v; v.w = 0;
    if (i < nmt * 11) {
      int xt = i / nmt, yt = i - xt * nmt;
      v.x = 0 | (meta[32 + yt] << 1); v.y = meta[80 + yt]; v.z = xt * 256;
    } else {
      int k = i - nmt * 11; int xt = k >> 4, yt = k & 15;
      v.x = 1; v.y = yt * 256; v.z = xt * 256;
    }
    gt[i] = v;
  }
  int4* dt4 = (int4*)(meta + 3328);
  const int nd = nmt * 8 + 256;
  for (int i = threadIdx.x; i < nd; i += 256) {
    int4 v; v.w = 0;
    if (i < nmt * 8) {
      int xt = i / nmt, yt = i - xt * nmt;
      v.x = 0 | (meta[32 + yt] << 1); v.y = meta[80 + yt]; v.z = xt * 256;
    } else {
      int k = i - nmt * 8; int xt = k >> 5, rem = k & 31, ks = rem >> 4, yt = rem & 15;
      v.x = 1 | (ks << 4); v.y = yt * 256; v.z = xt * 256;
    }
    dt4[i] = v;
  }
}

__global__ void scatter_kernel(const int* __restrict__ tk_i, const float* __restrict__ tk_w,
                               int* __restrict__ meta, int* __restrict__ tok_idx,
                               int* __restrict__ tk_slot) {
  int t = blockIdx.x * 256 + threadIdx.x;
  if (t >= T_TOK) return;
#pragma unroll
  for (int k = 0; k < 2; k++) {
    int e = tk_i[t * 2 + k];
    int pos = meta[16 + e] + atomicAdd(&meta[8 + e], 1);
    tok_idx[pos] = t; tk_slot[t * 2 + k] = pos;
  }
}

// ---------------- fused 8-phase 256x256 GEMM over a device tile table ----------------
// OP=0 gateup: A=xb; kind0: routed (gather, B=BguR[e], out=hid_r), kind1: shared
//   (B=BguS, +bias, out=hid_s). B is gate/up 16-col interleaved -> in-register SwiGLU.
// OP=1 down: kind0: routed (A=hid_r slots, B=dT[e], out=rt_p partial), kind1: shared
//   K-half ks (A=hid_s, B=sdT, out=sh_p[ks]). All partials bf16, no atomics.
template <int OP>
__global__ __launch_bounds__(512, 2)
void gemm8p(const bf16_t* __restrict__ A0, const bf16_t* __restrict__ A1,
            const bf16_t* __restrict__ B0, const bf16_t* __restrict__ B1,
            bf16_t* __restrict__ O0, bf16_t* __restrict__ O1, bf16_t* __restrict__ O2,
            const float* __restrict__ bg, const float* __restrict__ bu,
            const int* __restrict__ meta, const int* __restrict__ tok_idx) {
  const int ntiles = meta[OP == 0 ? 26 : 27];
  const int l = blockIdx.x;
  if (l >= ntiles) return;
  const int s = xcd_swz(l, ntiles);
  const int4 tv = ((const int4*)(meta + (OP == 0 ? 128 : 3328)))[s];
  const int kind = tv.x & 1, e = (tv.x >> 1) & 7, ks = (tv.x >> 4) & 1;
  const int row0 = tv.y, n0 = tv.z;

  int cnt, slot0 = 0, strideA, strideB, koffA = 0, koffB = 0;
  const bf16_t *Ab, *Bp;
  constexpr int NKT = (OP == 0) ? (HDIM / 64) : (IDIM / 64);  // 32 | 22 (both even, >=4)
  if (OP == 0) {
    strideA = HDIM; strideB = HDIM; Ab = A0;
    if (kind == 0) {
      slot0 = meta[16 + e]; cnt = meta[17 + e] - slot0;
      Bp = B0 + (size_t)e * (2 * IDIM) * HDIM;
    } else { cnt = T_TOK; Bp = B1; }
  } else {
    if (kind == 0) {
      slot0 = meta[16 + e]; cnt = meta[17 + e] - slot0;
      Ab = A0; strideA = IDIM;
      Bp = B0 + (size_t)e * HDIM * IDIM; strideB = IDIM;
    } else {
      cnt = T_TOK; Ab = A1; strideA = SIDIM; koffA = ks * IDIM;
      Bp = B1; strideB = SIDIM; koffB = ks * IDIM;
    }
  }

  __shared__ __align__(16) char smem[131072];

  const int t = threadIdx.x;
  const int lane = t & 63, wid = t >> 6;
  const int wr = wid >> 2, wc = wid & 3;
  const int lr = lane & 15, lg = lane >> 4;

  const bf16_t* pA[4]; const bf16_t* pB[4]; int dG[4];
#pragma unroll
  for (int j = 0; j < 4; ++j) {
    int g = j * 512 + t;
    int r = g >> 3;
    int c16 = (g & 7) ^ (r & 7);
    dG[j] = g * 16;
    int rr = row0 + r;
    if (kind == 0 && rr >= cnt) rr = cnt - 1;
    int arow;
    if (OP == 0 && kind == 0) arow = tok_idx[slot0 + rr];
    else if (OP == 1 && kind == 0) arow = slot0 + rr;
    else arow = rr;
    pA[j] = Ab + (size_t)arow * strideA + koffA + c16 * 8;
    pB[j] = Bp + (size_t)(n0 + r) * strideB + koffB + c16 * 8;
  }

  const int cswz0 = ((lg) ^ (lr & 7)) * 16;
  const int cswz1 = ((4 + lg) ^ (lr & 7)) * 16;
  const int aRowB = (wr * 128 + lr) * 128;
  const int bRowB = (wc * 64 + lr) * 128 + 65536;

  f32x4 acc[8][4];
#pragma unroll
  for (int mi = 0; mi < 8; ++mi)
#pragma unroll
    for (int ni = 0; ni < 4; ++ni) acc[mi][ni] = (f32x4)(0.f);

  bf16x8 aL[4][2], aH[4][2], bL[2][2], bH[2][2];

#define ST_A(BUFO, KT, JH) { \
    glds16(pA[(JH)*2]   + (KT)*64, smem + (BUFO) + dG[(JH)*2]); \
    glds16(pA[(JH)*2+1] + (KT)*64, smem + (BUFO) + dG[(JH)*2+1]); }
#define ST_B(BUFO, KT, JH) { \
    glds16(pB[(JH)*2]   + (KT)*64, smem + 65536 + (BUFO) + dG[(JH)*2]); \
    glds16(pB[(JH)*2+1] + (KT)*64, smem + 65536 + (BUFO) + dG[(JH)*2+1]); }
#define RD_A(af, BUFO, MIH) { \
    _Pragma("unroll") for (int mi = 0; mi < 4; ++mi) { \
      af[mi][0] = *(const bf16x8*)(smem + (BUFO) + aRowB + (MIH)*8192 + mi*2048 + cswz0); \
      af[mi][1] = *(const bf16x8*)(smem + (BUFO) + aRowB + (MIH)*8192 + mi*2048 + cswz1); } }
#define RD_B(bf, BUFO, NIH) { \
    _Pragma("unroll") for (int ni = 0; ni < 2; ++ni) { \
      bf[ni][0] = *(const bf16x8*)(smem + (BUFO) + bRowB + (NIH)*4096 + ni*2048 + cswz0); \
      bf[ni][1] = *(const bf16x8*)(smem + (BUFO) + bRowB + (NIH)*4096 + ni*2048 + cswz1); } }
#define MMQ(af, bf, MO, NO) { \
    __builtin_amdgcn_s_setprio(1); \
    _Pragma("unroll") for (int ni = 0; ni < 2; ++ni) \
    _Pragma("unroll") for (int mi = 0; mi < 4; ++mi) { \
      acc[(MO)+mi][(NO)+ni] = __builtin_amdgcn_mfma_f32_16x16x32_bf16(af[mi][0], bf[ni][0], acc[(MO)+mi][(NO)+ni], 0, 0, 0); \
      acc[(MO)+mi][(NO)+ni] = __builtin_amdgcn_mfma_f32_16x16x32_bf16(af[mi][1], bf[ni][1], acc[(MO)+mi][(NO)+ni], 0, 0, 0); } \
    __builtin_amdgcn_s_setprio(0); }
#define KTILE(KT, BO, NBO, W) { \
    RD_A(aL, BO, 0); RD_B(bL, BO, 0); \
    if ((KT) + 1 < NKT) ST_B(NBO, (KT) + 1, 0); \
    bar(); MMQ(aL, bL, 0, 0); bar(); \
    RD_A(aH, BO, 1); \
    if ((KT) + 1 < NKT) ST_B(NBO, (KT) + 1, 1); \
    bar(); MMQ(aH, bL, 4, 0); bar(); \
    RD_B(bH, BO, 1); \
    if ((KT) + 2 < NKT) ST_A(BO, (KT) + 2, 0); \
    bar(); MMQ(aH, bH, 4, 2); bar(); \
    if ((KT) + 2 < NKT) ST_A(BO, (KT) + 2, 1); \
    bar(); MMQ(aL, bH, 0, 2); \
    W; bar(); }

  ST_A(0, 0, 0); ST_A(0, 0, 1);
  ST_B(0, 0, 0); ST_B(0, 0, 1);
  ST_A(32768, 1, 0); ST_A(32768, 1, 1);
  VMW4; bar();

  // main loop: steady-state vmcnt(4). Tail peeled: tile NKT-2 issues only B(NKT-1)
  // (no A(NKT)), so vmcnt(4) would NOT guarantee B(NKT-1) landed -> full drain.
  for (int kt = 0; kt < NKT - 2; kt += 2) {
    KTILE(kt, 0, 32768, VMW4);
    KTILE(kt + 1, 32768, 0, VMW4);
  }
  KTILE(NKT - 2, 0, 32768, VMW0);
  KTILE(NKT - 1, 32768, 0, VMW0);

  if (OP == 0) {
    // in-register SwiGLU: gate in acc[.][even], up in acc[.][odd] (16-col interleave)
    bf16_t* Ho = kind ? O1 : O0;
    const int HN = kind ? SIDIM : IDIM;
    const int Lbase = n0 >> 1;
#pragma unroll
    for (int mi = 0; mi < 8; ++mi)
#pragma unroll
      for (int j = 0; j < 4; ++j) {
        int row = wr * 128 + mi * 16 + lg * 4 + j;
        int grow = row0 + row;
        if (kind == 0 && grow >= cnt) continue;
        size_t orow = (size_t)((kind ? 0 : slot0) + grow);
#pragma unroll
        for (int nih = 0; nih < 2; ++nih) {
          int Lr = wc * 32 + nih * 16 + lr;
          float g = acc[mi][2 * nih][j];
          float u = acc[mi][2 * nih + 1][j];
          if (kind) { g += bg[Lbase + Lr]; u += bu[Lbase + Lr]; }
          float h = (g / (1.f + __expf(-g))) * u;
          Ho[orow * HN + Lbase + Lr] = (bf16_t)h;
        }
      }
  } else {
    bf16_t* Po = kind ? (ks ? O2 : O1) : O0;
#pragma unroll
    for (int mi = 0; mi < 8; ++mi)
#pragma unroll
      for (int j = 0; j < 4; ++j) {
        int row = wr * 128 + mi * 16 + lg * 4 + j;
        int grow = row0 + row;
        if (kind == 0 && grow >= cnt) continue;
        size_t orow = (size_t)((kind ? 0 : slot0) + grow);
#pragma unroll
        for (int ni = 0; ni < 4; ++ni) {
          int col = n0 + wc * 64 + ni * 16 + lr;
          Po[orow * HDIM + col] = (bf16_t)acc[mi][ni][j];
        }
      }
  }
#undef ST_A
#undef ST_B
#undef RD_A
#undef RD_B
#undef MMQ
#undef KTILE
}

// out[t] = sh0[t]+sh1[t] + w1*rt[s1] + w2*rt[s2] + sdb
__global__ void combine_kernel(const bf16_t* __restrict__ sh0, const bf16_t* __restrict__ sh1,
                               const bf16_t* __restrict__ rt, const int* __restrict__ tk_slot,
                               const float* __restrict__ tk_w, const float* __restrict__ sdb,
                               float* __restrict__ out) {
  const int t = blockIdx.x;
  const int c = threadIdx.x * 8;
  const int s1 = tk_slot[2 * t], s2 = tk_slot[2 * t + 1];
  const float w1 = tk_w[2 * t], w2 = tk_w[2 * t + 1];
  bf16x8 a = *(const bf16x8*)(sh0 + (size_t)t * HDIM + c);
  bf16x8 b = *(const bf16x8*)(sh1 + (size_t)t * HDIM + c);
  bf16x8 r1 = *(const bf16x8*)(rt + (size_t)s1 * HDIM + c);
  bf16x8 r2 = *(const bf16x8*)(rt + (size_t)s2 * HDIM + c);
  float4 d0 = *(const float4*)(sdb + c);
  float4 d1 = *(const float4*)(sdb + c + 4);
  float o[8];
#pragma unroll
  for (int i = 0; i < 8; i++)
    o[i] = (float)a[i] + (float)b[i] + w1 * (float)r1[i] + w2 * (float)r2[i];
  o[0] += d0.x; o[1] += d0.y; o[2] += d0.z; o[3] += d0.w;
  o[4] += d1.x; o[5] += d1.y; o[6] += d1.z; o[7] += d1.w;
  float4* op = (float4*)(out + (size_t)t * HDIM + c);
  op[0] = make_float4(o[0], o[1], o[2], o[3]);
  op[1] = make_float4(o[4], o[5], o[6], o[7]);
}

extern "C" void kernel_launch(void* const* d_in, const int* in_sizes, int n_in,
                              void* d_out, int out_size, void* d_ws, size_t ws_size,
                              hipStream_t stream) {
  const float* x_f  = (const float*)d_in[0];
  const float* rw   = (const float*)d_in[1];
  const float* gate = (const float*)d_in[2];
  const float* up   = (const float*)d_in[3];
  const float* down = (const float*)d_in[4];
  const float* sgw  = (const float*)d_in[5];
  const float* sgb  = (const float*)d_in[6];
  const float* suw  = (const float*)d_in[7];
  const float* sub  = (const float*)d_in[8];
  const float* sdw  = (const float*)d_in[9];
  const float* sdb  = (const float*)d_in[10];
  float* out = (float*)d_out;

  char* ws = (char*)d_ws;
  size_t off = 0;
  auto alloc = [&](size_t bytes) {
    char* p = ws + off;
    off += (bytes + 255) & ~(size_t)255;
    return p;
  };
  bf16_t* xb    = (bf16_t*)alloc((size_t)T_TOK * HDIM * 2);
  char*   bgur  = alloc((size_t)NEXP * 2 * IDIM * HDIM * 2);            // 92.3MB
  bf16_t* BguR  = (bf16_t*)bgur;
  bf16_t* BguS  = (bf16_t*)alloc((size_t)2 * SIDIM * HDIM * 2);
  bf16_t* dT    = (bf16_t*)alloc((size_t)NEXP * HDIM * IDIM * 2);
  bf16_t* sdT   = (bf16_t*)alloc((size_t)HDIM * SIDIM * 2);
  bf16_t* hid_r = (bf16_t*)alloc((size_t)(T_TOK * 2) * IDIM * 2);
  bf16_t* hid_s = (bf16_t*)alloc((size_t)T_TOK * SIDIM * 2);
  int*    meta  = (int*)alloc(32768);
  int*    tok_idx = (int*)alloc(8192 * 4);
  int*    tk_slot = (int*)alloc(8192 * 4);
  int*    tk_i    = (int*)alloc((size_t)T_TOK * 2 * 4);
  float*  tk_w2   = (float*)alloc((size_t)T_TOK * 2 * 4);

  // down partials alias BguR (dead after gateup dispatch): 33.6+16.8+16.8 <= 92.3MB
  bf16_t* rt_p  = (bf16_t*)bgur;
  bf16_t* sh_p0 = (bf16_t*)(bgur + (size_t)8192 * HDIM * 2);
  bf16_t* sh_p1 = (bf16_t*)(bgur + (size_t)8192 * HDIM * 2 + (size_t)T_TOK * HDIM * 2);

  hipMemsetAsync(meta, 0, 64, stream);  // counts + cursor

  cvt_x_kernel<<<(T_TOK * HDIM / 4) / 256, 256, 0, stream>>>(
      (const float4*)x_f, (bf16x4*)xb, T_TOK * HDIM / 4);

  tcvt_gu_kernel<<<dim3(IDIM / 64, HDIM / 64, NEXP), 256, 0, stream>>>(gate, BguR, HDIM, IDIM, 0);
  tcvt_gu_kernel<<<dim3(IDIM / 64, HDIM / 64, NEXP), 256, 0, stream>>>(up,   BguR, HDIM, IDIM, 1);
  tcvt_gu_kernel<<<dim3(SIDIM / 64, HDIM / 64, 1), 256, 0, stream>>>(sgw, BguS, HDIM, SIDIM, 0);
  tcvt_gu_kernel<<<dim3(SIDIM / 64, HDIM / 64, 1), 256, 0, stream>>>(suw, BguS, HDIM, SIDIM, 1);
  tcvt_kernel<<<dim3(HDIM / 64, IDIM / 64, NEXP), 256, 0, stream>>>(down, dT, IDIM, HDIM);
  tcvt_kernel<<<dim3(HDIM / 64, SIDIM / 64, 1), 256, 0, stream>>>(sdw, sdT, SIDIM, HDIM);

  router_kernel<<<T_TOK / 4, 256, 0, stream>>>(x_f, rw, tk_i, tk_w2, meta);
  build_kernel<<<1, 256, 0, stream>>>(meta);
  scatter_kernel<<<T_TOK / 256, 256, 0, stream>>>(tk_i, tk_w2, meta, tok_idx, tk_slot);

  gemm8p<0><<<GU_CAP, 512, 0, stream>>>(
      xb, nullptr, BguR, BguS, hid_r, hid_s, nullptr, sgb, sub, meta, tok_idx);
  gemm8p<1><<<DN_CAP, 512, 0, stream>>>(
      hid_r, hid_s, dT, sdT, rt_p, sh_p0, sh_p1, nullptr, nullptr, meta, nullptr);
  combine_kernel<<<T_TOK, 256, 0, stream>>>(sh_p0, sh_p1, rt_p, tk_slot, tk_w2, sdb, out);
}